// Round 1
// baseline (316.119 us; speedup 1.0000x reference)
//
#include <hip/hip_runtime.h>
#include <stdint.h>

#define L1C 256
#define L2C 320
#define BC  64
#define DC  1024

typedef __bf16 bf16_t;
typedef __bf16 bf16x8 __attribute__((ext_vector_type(8)));
typedef __bf16 bf16x4 __attribute__((ext_vector_type(4)));
typedef float  f32x4  __attribute__((ext_vector_type(4)));

__device__ __forceinline__ void gload16(const void* g, void* l) {
  __builtin_amdgcn_global_load_lds(
      (__attribute__((address_space(1))) void*)g,
      (__attribute__((address_space(3))) void*)l, 16, 0, 0);
}

// ---------------- fp32 -> bf16 convert ----------------
__global__ __launch_bounds__(256)
void conv_kernel(const float* __restrict__ src, bf16_t* __restrict__ dst, int n4) {
  int i = blockIdx.x * 256 + threadIdx.x;
  const int stride = gridDim.x * 256;
  for (; i < n4; i += stride) {
    float4 v = ((const float4*)src)[i];
    bf16x4 o = { (__bf16)v.x, (__bf16)v.y, (__bf16)v.z, (__bf16)v.w };
    ((bf16x4*)dst)[i] = o;
  }
}

// ---------------- MLP GEMM: C[m,n] = sum_k A[m,k]*W[n,k] + bias[n] (opt relu) ----
// A: M x 1024 bf16 row-major, W: 1024 x 1024 bf16 row-major, C: M x 1024 bf16
__global__ __launch_bounds__(256)
void mlp_gemm(const bf16_t* __restrict__ A, const bf16_t* __restrict__ W,
              const float* __restrict__ bias, bf16_t* __restrict__ C,
              int Mtiles, int relu) {
  const int nwg = Mtiles * 8;
  const int wg  = ((int)blockIdx.x & 7) * (nwg >> 3) + ((int)blockIdx.x >> 3);
  const int mt = wg >> 3, nt = wg & 7;

  const int f = threadIdx.x;
  const int lane = f & 63, w = f >> 6;
  const int sRow = f >> 2, sCol8 = (f & 3) * 8;

  const bf16_t* Ab = A + (size_t)mt * 128 * 1024 + (size_t)sRow * 1024 + sCol8;
  const bf16_t* Bb = W + (size_t)nt * 128 * 1024 + (size_t)sRow * 1024 + sCol8;

  __shared__ __align__(16) bf16_t sA[128 * 32];
  __shared__ __align__(16) bf16_t sB[128 * 32];
  bf16_t* sAp = sA + sRow * 32 + sCol8;
  bf16_t* sBp = sB + sRow * 32 + sCol8;

  const int wr = (w >> 1) * 64, wc = (w & 1) * 64;
  const int rsel = lane & 15, koff = (lane >> 4) * 8;
  const bf16_t* rA = sA + (wr + rsel) * 32 + koff;
  const bf16_t* rB = sB + (wc + rsel) * 32 + koff;

  f32x4 acc[4][4] = {};
  for (int kt = 0; kt < 1024; kt += 32) {
    __syncthreads();
    gload16(Ab + kt,             sAp);
    gload16(Ab + kt + 64 * 1024, sAp + 64 * 32);
    gload16(Bb + kt,             sBp);
    gload16(Bb + kt + 64 * 1024, sBp + 64 * 32);
    asm volatile("s_waitcnt vmcnt(0)" ::: "memory");
    __syncthreads();
    bf16x8 af[4], bfv[4];
#pragma unroll
    for (int m = 0; m < 4; ++m) af[m] = *(const bf16x8*)(rA + m * 16 * 32);
#pragma unroll
    for (int n = 0; n < 4; ++n) bfv[n] = *(const bf16x8*)(rB + n * 16 * 32);
#pragma unroll
    for (int m = 0; m < 4; ++m)
#pragma unroll
      for (int n = 0; n < 4; ++n)
        acc[m][n] = __builtin_amdgcn_mfma_f32_16x16x32_bf16(af[m], bfv[n], acc[m][n], 0, 0, 0);
  }

  const int row0 = mt * 128 + wr + (lane >> 4) * 4;
  const int col0 = nt * 128 + wc + rsel;
#pragma unroll
  for (int n = 0; n < 4; ++n) {
    const int c = col0 + n * 16;
    const float bv = bias[c];
#pragma unroll
    for (int m = 0; m < 4; ++m) {
      const int r = row0 + m * 16;
#pragma unroll
      for (int q = 0; q < 4; ++q) {
        float v = acc[m][n][q] + bv;
        if (relu) v = fmaxf(v, 0.f);
        C[(size_t)(r + q) * 1024 + c] = (bf16_t)v;
      }
    }
  }
}

// ---------------- logits: o[b,i,j] = sum_d y1[b,i,d]*y2[b,j,d] ----------------
// y layout (L,B,D): row index = l*BC + b
__global__ __launch_bounds__(256)
void logits_gemm(const bf16_t* __restrict__ Y, float* __restrict__ O) {
  const int wg = ((int)blockIdx.x & 7) * 48 + ((int)blockIdx.x >> 3); // 384 blocks
  const int b = wg / 6, t = wg % 6;
  const int mt = t / 3, nt = t % 3;

  const int f = threadIdx.x;
  const int lane = f & 63, w = f >> 6;
  const int sRow = f >> 2, sCol8 = (f & 3) * 8;

  const bf16_t* Y1 = Y;
  const bf16_t* Y2 = Y + (size_t)L1C * BC * DC;

  const int i0 = mt * 128 + sRow;
  const int i1 = i0 + 64;
  int j0 = nt * 128 + sRow;      if (j0 > L2C - 1) j0 = L2C - 1;
  int j1 = nt * 128 + sRow + 64; if (j1 > L2C - 1) j1 = L2C - 1;
  const bf16_t* A0 = Y1 + ((size_t)i0 * BC + b) * DC + sCol8;
  const bf16_t* A1 = Y1 + ((size_t)i1 * BC + b) * DC + sCol8;
  const bf16_t* B0 = Y2 + ((size_t)j0 * BC + b) * DC + sCol8;
  const bf16_t* B1 = Y2 + ((size_t)j1 * BC + b) * DC + sCol8;

  __shared__ __align__(16) bf16_t sA[128 * 32];
  __shared__ __align__(16) bf16_t sB[128 * 32];
  bf16_t* sAp = sA + sRow * 32 + sCol8;
  bf16_t* sBp = sB + sRow * 32 + sCol8;

  const int wr = (w >> 1) * 64, wc = (w & 1) * 64;
  const int rsel = lane & 15, koff = (lane >> 4) * 8;
  const bf16_t* rA = sA + (wr + rsel) * 32 + koff;
  const bf16_t* rB = sB + (wc + rsel) * 32 + koff;

  f32x4 acc[4][4] = {};
  for (int kt = 0; kt < 1024; kt += 32) {
    __syncthreads();
    gload16(A0 + kt, sAp);
    gload16(A1 + kt, sAp + 64 * 32);
    gload16(B0 + kt, sBp);
    gload16(B1 + kt, sBp + 64 * 32);
    asm volatile("s_waitcnt vmcnt(0)" ::: "memory");
    __syncthreads();
    bf16x8 af[4], bfv[4];
#pragma unroll
    for (int m = 0; m < 4; ++m) af[m] = *(const bf16x8*)(rA + m * 16 * 32);
#pragma unroll
    for (int n = 0; n < 4; ++n) bfv[n] = *(const bf16x8*)(rB + n * 16 * 32);
#pragma unroll
    for (int m = 0; m < 4; ++m)
#pragma unroll
      for (int n = 0; n < 4; ++n)
        acc[m][n] = __builtin_amdgcn_mfma_f32_16x16x32_bf16(af[m], bfv[n], acc[m][n], 0, 0, 0);
  }

  float* Ob = O + (size_t)b * L1C * L2C;
  const int row0 = mt * 128 + wr + (lane >> 4) * 4;
  const int col0 = nt * 128 + wc + rsel;
#pragma unroll
  for (int n = 0; n < 4; ++n) {
    const int c = col0 + n * 16;
    if (c < L2C) {
#pragma unroll
      for (int m = 0; m < 4; ++m) {
        const int r = row0 + m * 16;
#pragma unroll
        for (int q = 0; q < 4; ++q)
          Ob[(size_t)(r + q) * L2C + c] = acc[m][n][q];
      }
    }
  }
}

// ---------------- softmax stats ----------------
// per-(b,i) row max + 1/sum over j   (softmax axis=2)
__global__ __launch_bounds__(256)
void row_stats(const float* __restrict__ O, float* __restrict__ rowM,
               float* __restrict__ rowInv) {
  const int gw = blockIdx.x * 4 + (threadIdx.x >> 6);  // b*256+i
  const int lane = threadIdx.x & 63;
  const float* row = O + (size_t)gw * L2C;
  float v[5];
  float m = -1e30f;
#pragma unroll
  for (int t = 0; t < 5; ++t) { v[t] = row[t * 64 + lane]; m = fmaxf(m, v[t]); }
#pragma unroll
  for (int off = 32; off; off >>= 1) m = fmaxf(m, __shfl_xor(m, off));
  float s = 0.f;
#pragma unroll
  for (int t = 0; t < 5; ++t) s += __expf(v[t] - m);
#pragma unroll
  for (int off = 32; off; off >>= 1) s += __shfl_xor(s, off);
  if (lane == 0) { rowM[gw] = m; rowInv[gw] = 1.f / s; }
}

// per-(b,j): online column max/sum (softmax axis=1)  AND  c1[b,j]=sum_i softmax_row[i,j]
__global__ __launch_bounds__(256)
void col_stats_c1(const float* __restrict__ O, const float* __restrict__ rowM,
                  const float* __restrict__ rowInv, float* __restrict__ colM,
                  float* __restrict__ colInv, float* __restrict__ c1) {
  const int b = blockIdx.x / 5, jb = blockIdx.x % 5;
  const int jl = threadIdx.x & 63, ig = threadIdx.x >> 6;
  const int j = jb * 64 + jl;
  const float* Ob = O + (size_t)b * L1C * L2C + j;
  const float* rM = rowM + b * L1C;
  const float* rI = rowInv + b * L1C;
  float m = -1e30f, s = 0.f, cp = 0.f;
  for (int i = ig; i < L1C; i += 4) {
    float v = Ob[(size_t)i * L2C];
    float mn = fmaxf(m, v);
    s = s * __expf(m - mn) + __expf(v - mn);
    m = mn;
    cp += __expf(v - rM[i]) * rI[i];
  }
  __shared__ float sm[4][64], ss[4][64], sc[4][64];
  sm[ig][jl] = m; ss[ig][jl] = s; sc[ig][jl] = cp;
  __syncthreads();
  if (ig == 0) {
    for (int g = 1; g < 4; ++g) {
      float mg = sm[g][jl], sg = ss[g][jl];
      float mn = fmaxf(m, mg);
      s = s * __expf(m - mn) + sg * __expf(mg - mn);
      m = mn;
      cp += sc[g][jl];
    }
    colM[b * L2C + j] = m;
    colInv[b * L2C + j] = 1.f / s;
    c1[b * L2C + j] = cp;
  }
}

// c2[b,i] = sum_j softmax_col[i,j]
__global__ __launch_bounds__(256)
void c2_kernel(const float* __restrict__ O, const float* __restrict__ colM,
               const float* __restrict__ colInv, float* __restrict__ c2) {
  const int gw = blockIdx.x * 4 + (threadIdx.x >> 6);  // b*256+i
  const int lane = threadIdx.x & 63;
  const int b = gw >> 8;
  const float* row = O + (size_t)gw * L2C;
  const float* cM = colM + b * L2C;
  const float* cI = colInv + b * L2C;
  float s = 0.f;
#pragma unroll
  for (int t = 0; t < 5; ++t) {
    const int j = t * 64 + lane;
    s += __expf(row[j] - cM[j]) * cI[j];
  }
#pragma unroll
  for (int off = 32; off; off >>= 1) s += __shfl_xor(s, off);
  if (lane == 0) c2[gw] = s;
}

// ---------------- pools ----------------
// out0[b, 0:1024]    = mean_i y1[b,i,:]        (/256)
// out1[b, 1024:2048] = (1/320) sum_i c2[b,i] y1[b,i,:]
__global__ __launch_bounds__(256)
void pool_y1(const bf16_t* __restrict__ Y1, const float* __restrict__ c2,
             float* __restrict__ out) {
  const int b = blockIdx.x >> 2;
  const int d = (blockIdx.x & 3) * 256 + threadIdx.x;
  float s1 = 0.f, s2 = 0.f;
  const float* c2b = c2 + b * L1C;
  for (int i = 0; i < L1C; ++i) {
    float v = (float)Y1[((size_t)i * BC + b) * DC + d];
    s1 += v;
    s2 += c2b[i] * v;
  }
  out[(size_t)b * 2048 + d] = s1 * (1.f / L1C);
  out[(size_t)BC * 2048 + (size_t)b * 2048 + 1024 + d] = s2 * (1.f / L2C);
}

// out1[b, 0:1024]    = mean_j y2[b,j,:]        (/320)
// out0[b, 1024:2048] = (1/256) sum_j c1[b,j] y2[b,j,:]
__global__ __launch_bounds__(256)
void pool_y2(const bf16_t* __restrict__ Y2, const float* __restrict__ c1,
             float* __restrict__ out) {
  const int b = blockIdx.x >> 2;
  const int d = (blockIdx.x & 3) * 256 + threadIdx.x;
  float s1 = 0.f, s2 = 0.f;
  const float* c1b = c1 + b * L2C;
  for (int j = 0; j < L2C; ++j) {
    float v = (float)Y2[((size_t)j * BC + b) * DC + d];
    s1 += v;
    s2 += c1b[j] * v;
  }
  out[(size_t)BC * 2048 + (size_t)b * 2048 + d] = s1 * (1.f / L2C);
  out[(size_t)b * 2048 + 1024 + d] = s2 * (1.f / L1C);
}

// ---------------- host ----------------
extern "C" void kernel_launch(void* const* d_in, const int* in_sizes, int n_in,
                              void* d_out, int out_size, void* d_ws, size_t ws_size,
                              hipStream_t stream) {
  const float* r1 = (const float*)d_in[0];
  const float* r2 = (const float*)d_in[1];
  const float* W1 = (const float*)d_in[2];
  const float* b1 = (const float*)d_in[3];
  const float* W2 = (const float*)d_in[4];
  const float* b2 = (const float*)d_in[5];
  float* out = (float*)d_out;
  char* ws = (char*)d_ws;

  const size_t M1 = (size_t)L1C * BC;   // 16384
  const size_t M2 = (size_t)L2C * BC;   // 20480
  const size_t Mt = M1 + M2;            // 36864

  size_t off = 0;
  bf16_t* XB  = (bf16_t*)(ws + off); off += Mt * DC * 2;        // region A (reused as YB)
  bf16_t* HB  = (bf16_t*)(ws + off); off += Mt * DC * 2;        // region B (reused as O)
  bf16_t* WB1 = (bf16_t*)(ws + off); off += (size_t)DC * DC * 2;
  bf16_t* WB2 = (bf16_t*)(ws + off); off += (size_t)DC * DC * 2;
  float* rowM   = (float*)(ws + off); off += 65536;
  float* rowInv = (float*)(ws + off); off += 65536;
  float* colM   = (float*)(ws + off); off += 81920;
  float* colInv = (float*)(ws + off); off += 81920;
  float* c1v    = (float*)(ws + off); off += 81920;
  float* c2v    = (float*)(ws + off); off += 65536;

  bf16_t* YB = XB;            // GEMM2 output overwrites XB (dead after GEMM1)
  float*  O  = (float*)HB;    // logits overwrite HB (dead after GEMM2)

  // 1. convert inputs to bf16
  conv_kernel<<<2048, 256, 0, stream>>>(r1, XB,            (int)(M1 * DC / 4));
  conv_kernel<<<2048, 256, 0, stream>>>(r2, XB + M1 * DC,  (int)(M2 * DC / 4));
  conv_kernel<<<512,  256, 0, stream>>>(W1, WB1, (int)((size_t)DC * DC / 4));
  conv_kernel<<<512,  256, 0, stream>>>(W2, WB2, (int)((size_t)DC * DC / 4));

  // 2. MLP: h = relu(x W1^T + b1); y = h W2^T + b2
  mlp_gemm<<<288 * 8, 256, 0, stream>>>(XB, WB1, b1, HB, 288, 1);
  mlp_gemm<<<288 * 8, 256, 0, stream>>>(HB, WB2, b2, YB, 288, 0);

  // 3. logits o[b,i,j]
  logits_gemm<<<384, 256, 0, stream>>>(YB, O);

  // 4. softmax statistics + attention column/row mass
  row_stats<<<4096, 256, 0, stream>>>(O, rowM, rowInv);
  col_stats_c1<<<320, 256, 0, stream>>>(O, rowM, rowInv, colM, colInv, c1v);
  c2_kernel<<<4096, 256, 0, stream>>>(O, colM, colInv, c2v);

  // 5. pooled outputs
  pool_y1<<<256, 256, 0, stream>>>(YB, c2v, out);
  pool_y2<<<256, 256, 0, stream>>>(YB + M1 * DC, c1v, out);
}